// Round 8
// baseline (88.754 us; speedup 1.0000x reference)
//
#include <hip/hip_runtime.h>
#include <math.h>

// Problem constants: N=8, S=4096, C=2, V=128, K=512
#define N_TOK   32768
#define C_CH    2
#define V_DIM   128
#define K_CODES 512
#define TPB     64           // tokens per block
#define BAND    4.0e-3f      // >= 2*beta, beta = rigorous bf16-screen error bound

typedef short     bf16v8 __attribute__((ext_vector_type(8)));
typedef float     f32x4  __attribute__((ext_vector_type(4)));
typedef unsigned  u32x4  __attribute__((ext_vector_type(4)));
typedef __attribute__((address_space(1))) const unsigned char* gas_t;
typedef __attribute__((address_space(3))) unsigned char* las_t;

// Explicit counted waits (the compiler will NOT synthesize these across
// global_load_lds -> ds_read without a barrier; rule #18: sched_barrier after)
#define WAITV(n) do { asm volatile("s_waitcnt vmcnt(" #n ")" ::: "memory"); \
                      __builtin_amdgcn_sched_barrier(0); } while (0)
#define WAITL()  do { asm volatile("s_waitcnt lgkmcnt(0)" ::: "memory");    \
                      __builtin_amdgcn_sched_barrier(0); } while (0)

// round-to-nearest-even fp32 -> bf16
__device__ inline unsigned f2bf(float f) {
    unsigned u = __float_as_uint(f);
    return (u + 0x7FFFu + ((u >> 16) & 1u)) >> 16;
}
__device__ inline unsigned mapf(float d) {          // order-preserving f32->u32
    unsigned u = __float_as_uint(d);
    return ((int)u < 0) ? ~u : (u | 0x80000000u);
}
__device__ inline float unmapf(unsigned u) {
    return __uint_as_float((u & 0x80000000u) ? (u & 0x7FFFFFFFu) : ~u);
}

// ---------------------------------------------------------------------------
// Kernel 0: ||e||^2, zero hist, build pre-swizzled bf16 e-image:
// img[(row*16 + sp)*16B] = e_row[slot sp ^ (k&7)] (8 bf16 per 16B slot).
// ---------------------------------------------------------------------------
__global__ __launch_bounds__(64) void vq_prep(const float* __restrict__ emb,
                                              float* __restrict__ e_sq,
                                              unsigned int* __restrict__ hist,
                                              unsigned char* __restrict__ img) {
    const int row  = blockIdx.x;          // c*512 + k
    const int k    = row & (K_CODES - 1);
    const int lane = threadIdx.x;
    const float a = emb[(size_t)row * V_DIM + lane];
    const float b = emb[(size_t)row * V_DIM + 64 + lane];
    float s = a * a + b * b;
#pragma unroll
    for (int off = 32; off; off >>= 1) s += __shfl_down(s, off);
    if (lane == 0) {
        e_sq[row] = s;
        if (row < K_CODES) hist[row] = 0u;
    }
    if (lane < 16) {
        const int sp = lane;
        const int sl = sp ^ (k & 7);
        const float* src = emb + (size_t)row * V_DIM + sl * 8;
        u32x4 val;
#pragma unroll
        for (int q = 0; q < 4; ++q)
            val[q] = f2bf(src[2 * q]) | (f2bf(src[2 * q + 1]) << 16);
        *reinterpret_cast<u32x4*>(img + ((size_t)row * 16 + sp) * 16) = val;
    }
}

// ---------------------------------------------------------------------------
// Kernel 1: main VQ. grid (512, 2), block 256 (4 waves).
// Each wave: A = all 64 tokens (4 M-tiles in VGPRs) x private 128-code slice,
// double-buffered per-wave LDS chunks (16 codes = 4 KB). Main loop has NO
// __syncthreads(); correctness comes from explicit counted vmcnt waits.
// ---------------------------------------------------------------------------
__global__ __launch_bounds__(256, 2) void vq_main(const float* __restrict__ x0,
                                                  const float* __restrict__ emb,
                                                  const float* __restrict__ e_sq,
                                                  const unsigned char* __restrict__ img,
                                                  unsigned int* __restrict__ hist,
                                                  float* __restrict__ out0,
                                                  float* __restrict__ out1,
                                                  float* __restrict__ out2) {
    __shared__ __align__(16) float xs[TPB * 132];          // 33792 B fp32, padded
    __shared__ __align__(16) unsigned char esA[4][4096];   // per-wave chunk buf A
    __shared__ __align__(16) unsigned char esB[4][4096];   // per-wave chunk buf B
    __shared__ float esq_s[K_CODES];
    __shared__ float xx_s[TPB];
    __shared__ unsigned int dmin_s[TPB];
    __shared__ unsigned long long best_s[TPB];
    __shared__ unsigned int cand[1024];
    __shared__ int cand_n;

    const int c    = blockIdx.y;
    const int gt0  = blockIdx.x * TPB;
    const int t    = threadIdx.x;
    const int lane = t & 63;
    const int w    = t >> 6;
    const int l15  = lane & 15;
    const int l4   = lane >> 4;

    // ---- stage x (fp32, padded rows) + ||x||^2 ----
#pragma unroll
    for (int it = 0; it < 8; ++it) {
        const int row = it * 8 + w * 2 + (lane >> 5);
        const int col = (lane & 31) * 4;
        const f32x4 xv = *reinterpret_cast<const f32x4*>(
            x0 + ((size_t)(gt0 + row) * C_CH + c) * V_DIM + col);
        *reinterpret_cast<f32x4*>(&xs[row * 132 + col]) = xv;
        float part = xv[0] * xv[0] + xv[1] * xv[1] + xv[2] * xv[2] + xv[3] * xv[3];
#pragma unroll
        for (int m2 = 1; m2 <= 16; m2 <<= 1) part += __shfl_xor(part, m2);
        if ((lane & 31) == 0) xx_s[row] = part;
    }
    esq_s[t]       = e_sq[c * K_CODES + t];
    esq_s[t + 256] = e_sq[c * K_CODES + 256 + t];
    if (t < TPB) { best_s[t] = ~0ull; dmin_s[t] = 0xFFFFFFFFu; }
    if (t == 0) cand_n = 0;
    __syncthreads();

    // ---- A fragments: 4 M-tiles x 4 k-chunks from fp32 xs (RNE to bf16) ----
    u32x4 Af[4][4];
#pragma unroll
    for (int m = 0; m < 4; ++m)
#pragma unroll
        for (int kk = 0; kk < 4; ++kk) {
            const float* xr = &xs[(m * 16 + l15) * 132 + kk * 32 + l4 * 8];
            const f32x4 lo = *reinterpret_cast<const f32x4*>(xr);
            const f32x4 hi = *reinterpret_cast<const f32x4*>(xr + 4);
            u32x4 v;
            v[0] = f2bf(lo[0]) | (f2bf(lo[1]) << 16);
            v[1] = f2bf(lo[2]) | (f2bf(lo[3]) << 16);
            v[2] = f2bf(hi[0]) | (f2bf(hi[1]) << 16);
            v[3] = f2bf(hi[2]) | (f2bf(hi[3]) << 16);
            Af[m][kk] = v;
        }

    unsigned char* bA = esA[w];
    unsigned char* bB = esB[w];
    const unsigned char* imgc = img + ((size_t)c * K_CODES) * 256;

    auto STAGE = [&](unsigned char* buf, int chunk) {
        const unsigned char* src = imgc + (size_t)(w * 128 + chunk * 16) * 256;
#pragma unroll
        for (int p = 0; p < 4; ++p)
            __builtin_amdgcn_global_load_lds(
                (gas_t)(src + (size_t)(p * 64 + lane) * 16),
                (las_t)(buf + p * 1024), 16, 0, 0);
    };

    float rmin[4][4];
#pragma unroll
    for (int m = 0; m < 4; ++m)
#pragma unroll
        for (int r = 0; r < 4; ++r) rmin[m][r] = INFINITY;
    float dminv[4][4];

    auto COMPUTE = [&](const unsigned char* buf, int chunk, bool collect) {
        const int kglob = w * 128 + chunk * 16 + l15;
        f32x4 acc[4] = {{0.f,0.f,0.f,0.f},{0.f,0.f,0.f,0.f},
                        {0.f,0.f,0.f,0.f},{0.f,0.f,0.f,0.f}};
#pragma unroll
        for (int kk = 0; kk < 4; ++kk) {
            const int sp = (kk * 4 + l4) ^ (kglob & 7);
            const bf16v8 B = __builtin_bit_cast(bf16v8,
                *reinterpret_cast<const u32x4*>(buf + l15 * 256 + sp * 16));
#pragma unroll
            for (int m = 0; m < 4; ++m)
                acc[m] = __builtin_amdgcn_mfma_f32_16x16x32_bf16(
                    __builtin_bit_cast(bf16v8, Af[m][kk]), B, acc[m], 0, 0, 0);
        }
        const float esv = esq_s[kglob];
        if (!collect) {
#pragma unroll
            for (int m = 0; m < 4; ++m)
#pragma unroll
                for (int r = 0; r < 4; ++r)
                    rmin[m][r] = fminf(rmin[m][r], fmaf(-2.f, acc[m][r], esv));
        } else {
#pragma unroll
            for (int m = 0; m < 4; ++m)
#pragma unroll
                for (int r = 0; r < 4; ++r) {
                    const float d = fmaf(-2.f, acc[m][r], esv);
                    if (d <= dminv[m][r]) {
                        const int tok = m * 16 + l4 * 4 + r;
                        const int pos = atomicAdd(&cand_n, 1);
                        if (pos < 1024)
                            cand[pos] = ((unsigned)tok << 9) | (unsigned)kglob;
                    }
                }
        }
    };

    // Explicitly-waited double-buffered pipeline. Steady state: 8 loads in
    // flight; WAITV(4) retires the older buffer's 4; WAITL() before each
    // re-STAGE kills the ds_read WAR hazard on the buffer being overwritten.
#define SWEEP(collect)                                                    \
    do {                                                                  \
        STAGE(bA, 0);                                                     \
        STAGE(bB, 1);                                                     \
        WAITV(4); COMPUTE(bA, 0, collect);                                \
        WAITL();  STAGE(bA, 2);                                           \
        WAITV(4); COMPUTE(bB, 1, collect);                                \
        WAITL();  STAGE(bB, 3);                                           \
        WAITV(4); COMPUTE(bA, 2, collect);                                \
        WAITL();  STAGE(bA, 4);                                           \
        WAITV(4); COMPUTE(bB, 3, collect);                                \
        WAITL();  STAGE(bB, 5);                                           \
        WAITV(4); COMPUTE(bA, 4, collect);                                \
        WAITL();  STAGE(bA, 6);                                           \
        WAITV(4); COMPUTE(bB, 5, collect);                                \
        WAITL();  STAGE(bB, 7);                                           \
        WAITV(4); COMPUTE(bA, 6, collect);                                \
        WAITV(0); COMPUTE(bB, 7, collect);                                \
    } while (0)

    // ---- sweep 1: running min ----
    SWEEP(false);

    // cross-lane min over 16 code-columns, then cross-wave via LDS atomicMin
#pragma unroll
    for (int m = 0; m < 4; ++m)
#pragma unroll
        for (int r = 0; r < 4; ++r) {
            float v = rmin[m][r];
#pragma unroll
            for (int s = 1; s < 16; s <<= 1) v = fminf(v, __shfl_xor(v, s));
            if (l15 == 0) atomicMin(&dmin_s[m * 16 + l4 * 4 + r], mapf(v));
        }
    __syncthreads();
#pragma unroll
    for (int m = 0; m < 4; ++m)
#pragma unroll
        for (int r = 0; r < 4; ++r)
            dminv[m][r] = unmapf(dmin_s[m * 16 + l4 * 4 + r]) + BAND;

    // ---- sweep 2: collect candidates (bit-identical recompute) ----
    SWEEP(true);
    __syncthreads();

    // ---- exact fp32 phase over candidates (x from fp32 LDS) ----
    const int n = cand_n < 1024 ? cand_n : 1024;
    for (int i = t; i < n; i += 256) {
        const unsigned key = cand[i];
        const int tok = key >> 9;
        const int kc  = key & (K_CODES - 1);
        const float* xg = &xs[tok * 132];
        const float* eg = emb + ((size_t)c * K_CODES + kc) * V_DIM;
        float a0 = 0.f, a1 = 0.f, a2 = 0.f, a3 = 0.f;
#pragma unroll
        for (int q = 0; q < 32; ++q) {
            const f32x4 xv = *reinterpret_cast<const f32x4*>(xg + q * 4);
            const f32x4 ev = *reinterpret_cast<const f32x4*>(eg + q * 4);
            a0 = fmaf(xv[0], ev[0], a0);
            a1 = fmaf(xv[1], ev[1], a1);
            a2 = fmaf(xv[2], ev[2], a2);
            a3 = fmaf(xv[3], ev[3], a3);
        }
        const float dot = (a0 + a1) + (a2 + a3);
        const float d   = fmaf(-2.f, dot, esq_s[kc]);
        atomicMin(&best_s[tok], ((unsigned long long)mapf(d) << 32) | (unsigned)kc);
    }
    __syncthreads();

    // ---- out1/out2/hist ----
    if (t < TPB) {
        const unsigned long long b = best_s[t];
        const int k = (int)(b & (unsigned)(K_CODES - 1));
        const float d = unmapf((unsigned)(b >> 32));
        const float o12 = xx_s[t] + d;
        const size_t oi = (size_t)(gt0 + t) * C_CH + c;
        out1[oi] = o12;
        out2[oi] = o12;
        atomicAdd(&hist[k], 1u);
    }

    // ---- out0 gather: (e - x) + x, x from fp32 LDS ----
#pragma unroll
    for (int i = 0; i < 8; ++i) {
        const int tok = i * 8 + (t >> 5);
        const int v4  = t & 31;
        const int k   = (int)(best_s[tok] & (unsigned long long)(K_CODES - 1));
        const f32x4 ev = *reinterpret_cast<const f32x4*>(
            emb + ((size_t)c * K_CODES + k) * V_DIM + v4 * 4);
        const f32x4 xv = *reinterpret_cast<const f32x4*>(&xs[tok * 132 + v4 * 4]);
        f32x4 ov;
#pragma unroll
        for (int z = 0; z < 4; ++z) ov[z] = (ev[z] - xv[z]) + xv[z];
        *reinterpret_cast<f32x4*>(
            out0 + ((size_t)(gt0 + tok) * C_CH + c) * V_DIM + v4 * 4) = ov;
    }
}

// ---------------------------------------------------------------------------
// Kernel 2: entropy over the 512-bin histogram (prob = hist / 32768).
// ---------------------------------------------------------------------------
__global__ __launch_bounds__(512) void vq_entropy(const unsigned int* __restrict__ hist,
                                                  float* __restrict__ ent) {
    const int t = threadIdx.x;
    float v = 0.f;
    const unsigned int h = hist[t];
    if (h > 0u) {
        const float p = (float)h * (1.0f / 32768.0f);
        v = p * logf(p);
    }
#pragma unroll
    for (int off = 32; off; off >>= 1) v += __shfl_down(v, off);
    __shared__ float s[8];
    if ((t & 63) == 0) s[t >> 6] = v;
    __syncthreads();
    if (t == 0) {
        float tot = 0.f;
#pragma unroll
        for (int i = 0; i < 8; ++i) tot += s[i];
        ent[0] = -tot;
    }
}

// ---------------------------------------------------------------------------
extern "C" void kernel_launch(void* const* d_in, const int* in_sizes, int n_in,
                              void* d_out, int out_size, void* d_ws, size_t ws_size,
                              hipStream_t stream) {
    const float* x0  = (const float*)d_in[0];   // (N,S,C,V) fp32
    const float* emb = (const float*)d_in[1];   // (C,K,V)   fp32

    float*         e_sq = (float*)d_ws;                          // 1024 f32
    unsigned int*  hist = (unsigned int*)((char*)d_ws + 4096);   // 512 u32
    unsigned char* img  = (unsigned char*)d_ws + 8192;           // 256 KB bf16 image

    float* out0 = (float*)d_out;
    float* out1 = out0 + (size_t)N_TOK * C_CH * V_DIM;
    float* out2 = out1 + (size_t)N_TOK * C_CH;
    float* ent  = out2 + (size_t)N_TOK * C_CH;

    vq_prep<<<C_CH * K_CODES, 64, 0, stream>>>(emb, e_sq, hist, img);
    vq_main<<<dim3(N_TOK / TPB, C_CH), 256, 0, stream>>>(x0, emb, e_sq, img, hist,
                                                         out0, out1, out2);
    vq_entropy<<<1, K_CODES, 0, stream>>>(hist, ent);
}

// Round 9
// 74.446 us; speedup vs baseline: 1.1922x; 1.1922x over previous
//
#include <hip/hip_runtime.h>
#include <math.h>

// Problem constants: N=8, S=4096, C=2, V=128, K=512
#define N_TOK    32768
#define C_CH     2
#define V_DIM    128
#define K_CODES  512
#define TPB      32          // tokens per block
#define CAND_CAP 512
#define BAND     4.0e-3f     // >= 2*beta; beta (rigorous bf16 screen bound) ~8e-4

typedef short     bf16v8 __attribute__((ext_vector_type(8)));
typedef float     f32x4  __attribute__((ext_vector_type(4)));
typedef unsigned  u32x4  __attribute__((ext_vector_type(4)));
typedef __attribute__((address_space(1))) const unsigned char* gas_t;
typedef __attribute__((address_space(3))) unsigned char* las_t;

// round-to-nearest-even fp32 -> bf16
__device__ inline unsigned f2bf(float f) {
    unsigned u = __float_as_uint(f);
    return (u + 0x7FFFu + ((u >> 16) & 1u)) >> 16;
}
__device__ inline unsigned mapf(float d) {          // order-preserving f32->u32
    unsigned u = __float_as_uint(d);
    return ((int)u < 0) ? ~u : (u | 0x80000000u);
}
__device__ inline float unmapf(unsigned u) {
    return __uint_as_float((u & 0x80000000u) ? (u & 0x7FFFFFFFu) : ~u);
}

// ---------------------------------------------------------------------------
// Kernel 0: ||e||^2, zero hist, build pre-swizzled bf16 e-image:
// img[(row*16 + sp)*16B] = e_row[slot sp ^ (k&7)] (8 bf16 per 16B slot).
// ---------------------------------------------------------------------------
__global__ __launch_bounds__(64) void vq_prep(const float* __restrict__ emb,
                                              float* __restrict__ e_sq,
                                              unsigned int* __restrict__ hist,
                                              unsigned char* __restrict__ img) {
    const int row  = blockIdx.x;          // c*512 + k
    const int k    = row & (K_CODES - 1);
    const int lane = threadIdx.x;
    const float a = emb[(size_t)row * V_DIM + lane];
    const float b = emb[(size_t)row * V_DIM + 64 + lane];
    float s = a * a + b * b;
#pragma unroll
    for (int off = 32; off; off >>= 1) s += __shfl_down(s, off);
    if (lane == 0) {
        e_sq[row] = s;
        if (row < K_CODES) hist[row] = 0u;
    }
    if (lane < 16) {
        const int sp = lane;
        const int sl = sp ^ (k & 7);
        const float* src = emb + (size_t)row * V_DIM + sl * 8;
        u32x4 val;
#pragma unroll
        for (int q = 0; q < 4; ++q)
            val[q] = f2bf(src[2 * q]) | (f2bf(src[2 * q + 1]) << 16);
        *reinterpret_cast<u32x4*>(img + ((size_t)row * 16 + sp) * 16) = val;
    }
}

// ---------------------------------------------------------------------------
// Kernel 1: main VQ. grid (1024, 2), block 256 (4 waves), 3 blocks/CU.
// 32 tokens/block; wave w owns codes [w*32, w*32+32) of each staged
// 128-code quarter (shared LDS, barrier cadence). Single MFMA sweep:
// all 64 screened distances per lane stay in VGPRs (dt[2][8][4], static
// indexing); candidate collection is a register re-scan, not a 2nd sweep.
// ---------------------------------------------------------------------------
__global__ __launch_bounds__(256, 3) void vq_main(const float* __restrict__ x0,
                                                  const float* __restrict__ emb,
                                                  const float* __restrict__ e_sq,
                                                  const unsigned char* __restrict__ img,
                                                  unsigned int* __restrict__ hist,
                                                  float* __restrict__ out0,
                                                  float* __restrict__ out1,
                                                  float* __restrict__ out2) {
    __shared__ __align__(16) unsigned char es[128 * 256];   // 32 KB e-quarter
    __shared__ __align__(16) unsigned char xs[TPB * 256];   // 8 KB x bf16 swizzled
    __shared__ float xx_s[TPB];
    __shared__ unsigned int dmin_s[TPB];
    __shared__ unsigned long long best_s[TPB];
    __shared__ unsigned int cand[CAND_CAP];
    __shared__ int cand_n;

    const int c    = blockIdx.y;
    const int gt0  = blockIdx.x * TPB;
    const int t    = threadIdx.x;
    const int lane = t & 63;
    const int w    = t >> 6;
    const int l15  = lane & 15;
    const int l4   = lane >> 4;

    if (t < TPB) { dmin_s[t] = 0xFFFFFFFFu; best_s[t] = ~0ull; }
    if (t == 0) cand_n = 0;

    // ---- stage x: fp32 -> bf16 (RNE) swizzled tile + ||x||^2 (fp32) ----
    {
        const int row = t >> 3;          // 0..31
        const int q   = t & 7;           // 16-float column group
        const float* xp = x0 + ((size_t)(gt0 + row) * C_CH + c) * V_DIM + q * 16;
        f32x4 p0 = *reinterpret_cast<const f32x4*>(xp);
        f32x4 p1 = *reinterpret_cast<const f32x4*>(xp + 4);
        f32x4 p2 = *reinterpret_cast<const f32x4*>(xp + 8);
        f32x4 p3 = *reinterpret_cast<const f32x4*>(xp + 12);
        float part = 0.f;
#pragma unroll
        for (int z = 0; z < 4; ++z) {
            part = fmaf(p0[z], p0[z], part);
            part = fmaf(p1[z], p1[z], part);
            part = fmaf(p2[z], p2[z], part);
            part = fmaf(p3[z], p3[z], part);
        }
#pragma unroll
        for (int m2 = 1; m2 <= 4; m2 <<= 1) part += __shfl_xor(part, m2);
        if (q == 0) xx_s[row] = part;
        u32x4 v0, v1;
        v0[0] = f2bf(p0[0]) | (f2bf(p0[1]) << 16);
        v0[1] = f2bf(p0[2]) | (f2bf(p0[3]) << 16);
        v0[2] = f2bf(p1[0]) | (f2bf(p1[1]) << 16);
        v0[3] = f2bf(p1[2]) | (f2bf(p1[3]) << 16);
        v1[0] = f2bf(p2[0]) | (f2bf(p2[1]) << 16);
        v1[1] = f2bf(p2[2]) | (f2bf(p2[3]) << 16);
        v1[2] = f2bf(p3[0]) | (f2bf(p3[1]) << 16);
        v1[3] = f2bf(p3[2]) | (f2bf(p3[3]) << 16);
        const int s0 = (q * 2)     ^ (row & 7);
        const int s1 = (q * 2 + 1) ^ (row & 7);
        *reinterpret_cast<u32x4*>(xs + row * 256 + s0 * 16) = v0;
        *reinterpret_cast<u32x4*>(xs + row * 256 + s1 * 16) = v1;
    }

    // ---- per-lane e_sq for this wave's 8 (Q,n) code columns ----
    float esq_r[8];
#pragma unroll
    for (int Q = 0; Q < 4; ++Q)
#pragma unroll
        for (int n = 0; n < 2; ++n)
            esq_r[Q * 2 + n] = e_sq[c * K_CODES + Q * 128 + w * 32 + n * 16 + l15];

    __syncthreads();

    // ---- A fragments: 2 M-tiles x 4 k-chunks (bf16, swizzled reads) ----
    u32x4 Af[2][4];
#pragma unroll
    for (int m = 0; m < 2; ++m)
#pragma unroll
        for (int kk = 0; kk < 4; ++kk) {
            const int row = m * 16 + l15;
            Af[m][kk] = *reinterpret_cast<const u32x4*>(
                xs + row * 256 + (((kk * 4 + l4) ^ (row & 7)) * 16));
        }

    // ---- single MFMA sweep; all 64 d~ per lane kept in registers ----
    float dt[2][8][4];
    const unsigned char* imgc = img + ((size_t)c * K_CODES) * 256;

#pragma unroll
    for (int Q = 0; Q < 4; ++Q) {
        __syncthreads();   // WAR: prior quarter's readers done
        {
            const unsigned char* src = imgc + (size_t)Q * 128 * 256;
#pragma unroll
            for (int i = 0; i < 8; ++i) {
                const int off = (i * 4 + w) * 1024;    // wave-uniform LDS dest
                __builtin_amdgcn_global_load_lds(
                    (gas_t)(src + off + lane * 16),
                    (las_t)(es + off), 16, 0, 0);
            }
        }
        __syncthreads();   // vmcnt drained by compiler; es ready

#pragma unroll
        for (int n = 0; n < 2; ++n) {
            const int row = w * 32 + n * 16 + l15;     // local code row
            u32x4 B[4];
#pragma unroll
            for (int kk = 0; kk < 4; ++kk)
                B[kk] = *reinterpret_cast<const u32x4*>(
                    es + row * 256 + (((kk * 4 + l4) ^ (row & 7)) * 16));
            f32x4 a0 = {0.f, 0.f, 0.f, 0.f};
            f32x4 a1 = {0.f, 0.f, 0.f, 0.f};
#pragma unroll
            for (int kk = 0; kk < 4; ++kk) {
                a0 = __builtin_amdgcn_mfma_f32_16x16x32_bf16(
                    __builtin_bit_cast(bf16v8, Af[0][kk]),
                    __builtin_bit_cast(bf16v8, B[kk]), a0, 0, 0, 0);
                a1 = __builtin_amdgcn_mfma_f32_16x16x32_bf16(
                    __builtin_bit_cast(bf16v8, Af[1][kk]),
                    __builtin_bit_cast(bf16v8, B[kk]), a1, 0, 0, 0);
            }
            const float esv = esq_r[Q * 2 + n];
#pragma unroll
            for (int r = 0; r < 4; ++r) {
                dt[0][Q * 2 + n][r] = fmaf(-2.f, a0[r], esv);
                dt[1][Q * 2 + n][r] = fmaf(-2.f, a1[r], esv);
            }
        }
    }

    // ---- per-token min: lane fold over 8 columns, shfl over 16 lanes ----
#pragma unroll
    for (int m = 0; m < 2; ++m)
#pragma unroll
        for (int r = 0; r < 4; ++r) {
            float v = dt[m][0][r];
#pragma unroll
            for (int qn = 1; qn < 8; ++qn) v = fminf(v, dt[m][qn][r]);
#pragma unroll
            for (int s = 1; s < 16; s <<= 1) v = fminf(v, __shfl_xor(v, s));
            if (l15 == 0) atomicMin(&dmin_s[m * 16 + l4 * 4 + r], mapf(v));
        }
    __syncthreads();

    // ---- register re-scan: collect candidates within BAND of m~ ----
#pragma unroll
    for (int m = 0; m < 2; ++m)
#pragma unroll
        for (int r = 0; r < 4; ++r) {
            const int tok = m * 16 + l4 * 4 + r;
            const float thr = unmapf(dmin_s[tok]) + BAND;
#pragma unroll
            for (int qn = 0; qn < 8; ++qn) {
                if (dt[m][qn][r] <= thr) {
                    const int k = (qn >> 1) * 128 + w * 32 + (qn & 1) * 16 + l15;
                    const int pos = atomicAdd(&cand_n, 1);
                    if (pos < CAND_CAP)
                        cand[pos] = ((unsigned)tok << 9) | (unsigned)k;
                }
            }
        }
    __syncthreads();

    // ---- exact fp32 phase over candidates (x, e, esq from global/L2) ----
    const int nc = cand_n < CAND_CAP ? cand_n : CAND_CAP;
    for (int i = t; i < nc; i += 256) {
        const unsigned key = cand[i];
        const int tok = key >> 9;
        const int kc  = key & (K_CODES - 1);
        const float* xg = x0 + ((size_t)(gt0 + tok) * C_CH + c) * V_DIM;
        const float* eg = emb + ((size_t)c * K_CODES + kc) * V_DIM;
        float a0 = 0.f, a1 = 0.f, a2 = 0.f, a3 = 0.f;
#pragma unroll 4
        for (int q = 0; q < 32; ++q) {
            const f32x4 xv = *reinterpret_cast<const f32x4*>(xg + q * 4);
            const f32x4 ev = *reinterpret_cast<const f32x4*>(eg + q * 4);
            a0 = fmaf(xv[0], ev[0], a0);
            a1 = fmaf(xv[1], ev[1], a1);
            a2 = fmaf(xv[2], ev[2], a2);
            a3 = fmaf(xv[3], ev[3], a3);
        }
        const float dot = (a0 + a1) + (a2 + a3);
        const float d   = fmaf(-2.f, dot, e_sq[c * K_CODES + kc]);
        atomicMin(&best_s[tok], ((unsigned long long)mapf(d) << 32) | (unsigned)kc);
    }
    __syncthreads();

    // ---- out1/out2/hist ----
    if (t < TPB) {
        const unsigned long long b = best_s[t];
        const int k = (int)(b & (unsigned)(K_CODES - 1));
        const float d = unmapf((unsigned)(b >> 32));
        const float o12 = xx_s[t] + d;
        const size_t oi = (size_t)(gt0 + t) * C_CH + c;
        out1[oi] = o12;
        out2[oi] = o12;
        atomicAdd(&hist[k], 1u);
    }

    // ---- out0 gather: (e - x) + x (fp32, L2-warm reads) ----
#pragma unroll
    for (int i = 0; i < 4; ++i) {
        const int tok = i * 8 + (t >> 5);
        const int v4  = t & 31;
        const int k   = (int)(best_s[tok] & (unsigned long long)(K_CODES - 1));
        const f32x4 ev = *reinterpret_cast<const f32x4*>(
            emb + ((size_t)c * K_CODES + k) * V_DIM + v4 * 4);
        const f32x4 xv = *reinterpret_cast<const f32x4*>(
            x0 + ((size_t)(gt0 + tok) * C_CH + c) * V_DIM + v4 * 4);
        f32x4 ov;
#pragma unroll
        for (int z = 0; z < 4; ++z) ov[z] = (ev[z] - xv[z]) + xv[z];
        *reinterpret_cast<f32x4*>(
            out0 + ((size_t)(gt0 + tok) * C_CH + c) * V_DIM + v4 * 4) = ov;
    }
}

// ---------------------------------------------------------------------------
// Kernel 2: entropy over the 512-bin histogram (prob = hist / 32768).
// ---------------------------------------------------------------------------
__global__ __launch_bounds__(512) void vq_entropy(const unsigned int* __restrict__ hist,
                                                  float* __restrict__ ent) {
    const int t = threadIdx.x;
    float v = 0.f;
    const unsigned int h = hist[t];
    if (h > 0u) {
        const float p = (float)h * (1.0f / 32768.0f);
        v = p * logf(p);
    }
#pragma unroll
    for (int off = 32; off; off >>= 1) v += __shfl_down(v, off);
    __shared__ float s[8];
    if ((t & 63) == 0) s[t >> 6] = v;
    __syncthreads();
    if (t == 0) {
        float tot = 0.f;
#pragma unroll
        for (int i = 0; i < 8; ++i) tot += s[i];
        ent[0] = -tot;
    }
}

// ---------------------------------------------------------------------------
extern "C" void kernel_launch(void* const* d_in, const int* in_sizes, int n_in,
                              void* d_out, int out_size, void* d_ws, size_t ws_size,
                              hipStream_t stream) {
    const float* x0  = (const float*)d_in[0];   // (N,S,C,V) fp32
    const float* emb = (const float*)d_in[1];   // (C,K,V)   fp32

    float*         e_sq = (float*)d_ws;                          // 1024 f32
    unsigned int*  hist = (unsigned int*)((char*)d_ws + 4096);   // 512 u32
    unsigned char* img  = (unsigned char*)d_ws + 8192;           // 256 KB bf16 image

    float* out0 = (float*)d_out;
    float* out1 = out0 + (size_t)N_TOK * C_CH * V_DIM;
    float* out2 = out1 + (size_t)N_TOK * C_CH;
    float* ent  = out2 + (size_t)N_TOK * C_CH;

    vq_prep<<<C_CH * K_CODES, 64, 0, stream>>>(emb, e_sq, hist, img);
    vq_main<<<dim3(N_TOK / TPB, C_CH), 256, 0, stream>>>(x0, emb, e_sq, img, hist,
                                                         out0, out1, out2);
    vq_entropy<<<1, K_CODES, 0, stream>>>(hist, ent);
}